// Round 12
// baseline (139.442 us; speedup 1.0000x reference)
//
#include <hip/hip_runtime.h>

typedef unsigned int u32;
typedef unsigned short u16;
typedef unsigned long long u64;
typedef __attribute__((ext_vector_type(8))) short s16x8;
typedef __attribute__((ext_vector_type(8))) __bf16 bf16x8;
typedef __attribute__((ext_vector_type(4))) float f32x4;
typedef __attribute__((ext_vector_type(16))) float f32x16;
typedef __attribute__((ext_vector_type(4))) u32 u32x4;

#define WSMB (1ull << 20)
#define QSC 0.18033688011112042f  // log2(e)/8, folded into Q projection

static __device__ __forceinline__ u16 f2bf(float f) {
  u32 u = __builtin_bit_cast(u32, f);
  return (u16)((u + 0x7fffu + ((u >> 16) & 1u)) >> 16);
}

// v_cvt_pk_bf16_f32: low16 = bf16(lo), high16 = bf16(hi)  (RNE)
static __device__ __forceinline__ u32 pkbf(float lo, float hi) {
  u32 r;
  asm("v_cvt_pk_bf16_f32 %0, %1, %2" : "=v"(r) : "v"(lo), "v"(hi));
  return r;
}

// native exp2
static __device__ __forceinline__ float ex2(float x) {
  float r;
  asm("v_exp_f32 %0, %1" : "=v"(r) : "v"(x));
  return r;
}

static __device__ __forceinline__ f32x4 mfma16x16(s16x8 a, s16x8 b, f32x4 c) {
  return __builtin_amdgcn_mfma_f32_16x16x32_bf16(
      __builtin_bit_cast(bf16x8, a), __builtin_bit_cast(bf16x8, b), c, 0, 0, 0);
}

static __device__ __forceinline__ f32x16 mfma32x32(s16x8 a, s16x8 b, f32x16 c) {
  return __builtin_amdgcn_mfma_f32_32x32x16_bf16(
      __builtin_bit_cast(bf16x8, a), __builtin_bit_cast(bf16x8, b), c, 0, 0, 0);
}

#define GLOAD_LDS16(g, l)                                                      \
  __builtin_amdgcn_global_load_lds(                                            \
      (const __attribute__((address_space(1))) u32*)(const void*)(g),          \
      (__attribute__((address_space(3))) u32*)(void*)(l), 16, 0, 0)

// ------- merged fp32->bf16 converts + mask bitmask (one 2D launch) ---------
// y 0-2: X q/k/v (4096 blocks); y 3-6: weights (1024 blocks); y 7: bits.
__global__ __launch_bounds__(256) void k_prep(
    const float* __restrict__ xq, const float* __restrict__ xk,
    const float* __restrict__ xv, const float* __restrict__ wq,
    const float* __restrict__ wk, const float* __restrict__ wv,
    const float* __restrict__ wo, const float* __restrict__ mask,
    u16* __restrict__ oxq, u16* __restrict__ oxk, u16* __restrict__ oxv,
    u16* __restrict__ owq, u16* __restrict__ owk, u16* __restrict__ owv,
    u16* __restrict__ owo, u64* __restrict__ bits) {
  const int y = blockIdx.y;
  if (y >= 3 && blockIdx.x >= 1024) return;
  if (y == 7) {  // mask -> 64-bit row bitmasks
    int w = threadIdx.x >> 6, l = threadIdx.x & 63;
    int r = blockIdx.x * 4 + w;
    float v = mask[(size_t)r * 64 + l];
    u64 bl = __ballot(v != 0.0f);
    if (l == 0) bits[r] = bl;
    return;
  }
  const float* s;
  u16* d;
  switch (y) {
    case 0: s = xq; d = oxq; break;
    case 1: s = xk; d = oxk; break;
    case 2: s = xv; d = oxv; break;
    case 3: s = wq; d = owq; break;
    case 4: s = wk; d = owk; break;
    case 5: s = wv; d = owv; break;
    default: s = wo; d = owo; break;
  }
  int i = (blockIdx.x * 256 + threadIdx.x) * 4;
  float4 v = *(const float4*)(s + i);
  u64 p = (u64)f2bf(v.x) | ((u64)f2bf(v.y) << 16) | ((u64)f2bf(v.z) << 32) |
          ((u64)f2bf(v.w) << 48);
  *(u64*)(d + i) = p;
}

// ---------------- mask bit-matrix: MB[qg][kt] bit j = row qg visible key kt*64+j
__global__ __launch_bounds__(256) void k_mm(const u64* __restrict__ bits,
                                            u64* __restrict__ MB) {
  int wv = threadIdx.x >> 6, l = threadIdx.x & 63;
  int qg = blockIdx.x * 4 + wv;  // 0..4095
  u64 bq = bits[qg];
  const u64* bb = bits + (qg & ~1023);
  u64* out = MB + (size_t)qg * 16;
  for (int kt = 0; kt < 16; kt++) {
    u64 bk = bb[kt * 64 + l];
    u64 m = __ballot((bq & bk) != 0ull);
    if (l == 0) out[kt] = m;
  }
}

// ------- shared GEMM core: C[128x128] = A[128xK] * B[128xK]^T --------------
static __device__ __forceinline__ void gemm_core(const u16* __restrict__ A,
                                                 const u16* __restrict__ Bw,
                                                 f32x4 (&acc)[4][4]) {
  __shared__ __attribute__((aligned(16))) u16 As[2][4096];
  __shared__ __attribute__((aligned(16))) u16 Bs[2][4096];
  const int t = threadIdx.x;
  const int l = t & 63, w = t >> 6, lr = l & 15, lk = l >> 4;
  const int amr = (w & 1) * 64, bnr = (w >> 1) * 64;
  const int c0 = t, c1 = t + 256;
  const int r0 = c0 >> 2, r1 = c1 >> 2;
  const int sw0 = ((c0 & 3) * 8) ^ ((r0 & 6) << 2);  // element offset in row
  const int sw1 = ((c1 & 3) * 8) ^ ((r1 & 6) << 2);
  const u16* Ag0 = A + (size_t)r0 * 1024 + sw0;
  const u16* Ag1 = A + (size_t)r1 * 1024 + sw1;
  const u16* Bg0 = Bw + (size_t)r0 * 1024 + sw0;
  const u16* Bg1 = Bw + (size_t)r1 * 1024 + sw1;
  const int aswz = (lk * 16) ^ ((lr & 6) << 3);  // byte offset in 64B row

  GLOAD_LDS16(Ag0, &As[0][c0 * 8]);
  GLOAD_LDS16(Ag1, &As[0][c1 * 8]);
  GLOAD_LDS16(Bg0, &Bs[0][c0 * 8]);
  GLOAD_LDS16(Bg1, &Bs[0][c1 * 8]);

  int cur = 0;
  for (int kt = 0; kt < 1024; kt += 32) {
    __syncthreads();  // drains cur loads + prev-iter LDS reads
    if (kt < 992) {
      const int nxt = cur ^ 1;
      GLOAD_LDS16(Ag0 + kt + 32, &As[nxt][c0 * 8]);
      GLOAD_LDS16(Ag1 + kt + 32, &As[nxt][c1 * 8]);
      GLOAD_LDS16(Bg0 + kt + 32, &Bs[nxt][c0 * 8]);
      GLOAD_LDS16(Bg1 + kt + 32, &Bs[nxt][c1 * 8]);
    }
    const char* Ac = (const char*)As[cur];
    const char* Bc = (const char*)Bs[cur];
    s16x8 af[4], bf[4];
#pragma unroll
    for (int i = 0; i < 4; i++)
      af[i] = *(const s16x8*)(Ac + (amr + i * 16 + lr) * 64 + aswz);
#pragma unroll
    for (int j = 0; j < 4; j++)
      bf[j] = *(const s16x8*)(Bc + (bnr + j * 16 + lr) * 64 + aswz);
    __builtin_amdgcn_s_setprio(1);
#pragma unroll
    for (int i = 0; i < 4; i++)
#pragma unroll
      for (int j = 0; j < 4; j++)
        acc[i][j] = mfma16x16(af[i], bf[j], acc[i][j]);
    __builtin_amdgcn_s_setprio(0);
    cur ^= 1;
  }
}

// ---------------- fused QKV projection ----------------
// Q/K: C^T orientation (rows=d, cols=s) -> packed b64 stores to [b,h][s][d].
// Q additionally scaled by QSC = log2(e)/8 (attn uses exp2 domain).
// V:   C orientation -> blocked V4[b,h][s>>3][d][s&7].
__global__ __launch_bounds__(256) void k_qkv(
    const u16* __restrict__ Xq, const u16* __restrict__ Xk,
    const u16* __restrict__ Xv, const u16* __restrict__ Wqb,
    const u16* __restrict__ Wkb, const u16* __restrict__ Wvb,
    const float* __restrict__ bq, const float* __restrict__ bk,
    const float* __restrict__ bv, u16* __restrict__ Qo, u16* __restrict__ Ko,
    u16* __restrict__ V4) {
  const int bid0 = blockIdx.x;
  const int bid = (bid0 & 7) * 96 + (bid0 >> 3);  // XCD swizzle (768%8==0)
  const int proj = bid >> 8;
  const int rem = bid & 255;
  const int st = rem >> 3, dt = rem & 7;
  const u16* Xp = proj == 0 ? Xq : (proj == 1 ? Xk : Xv);
  const u16* Wp = proj == 0 ? Wqb : (proj == 1 ? Wkb : Wvb);
  const float* bias = proj == 0 ? bq : (proj == 1 ? bk : bv);
  const int t = threadIdx.x;
  const int l = t & 63, w = t >> 6, lr = l & 15, lk = l >> 4;
  const int amr = (w & 1) * 64, bnr = (w >> 1) * 64;
  f32x4 acc[4][4] = {};
  if (proj < 2) {
    const float sc = proj == 0 ? QSC : 1.0f;
    gemm_core(Wp + (size_t)dt * 131072, Xp + (size_t)st * 131072, acc);
    u16* O = proj ? Ko : Qo;
#pragma unroll
    for (int i = 0; i < 4; i++) {
      const int d0 = dt * 128 + amr + i * 16 + lk * 4;
      const int h = d0 >> 6, dd0 = d0 & 63;
      const float4 b4 = *(const float4*)(bias + d0);
#pragma unroll
      for (int j = 0; j < 4; j++) {
        const int s = st * 128 + bnr + j * 16 + lr;
        const int b_ = s >> 10, si = s & 1023;
        u32 e0 = pkbf((acc[i][j][0] + b4.x) * sc, (acc[i][j][1] + b4.y) * sc);
        u32 e1 = pkbf((acc[i][j][2] + b4.z) * sc, (acc[i][j][3] + b4.w) * sc);
        *(u64*)(O + ((size_t)((b_ * 16 + h) * 1024 + si)) * 64 + dd0) =
            (u64)e0 | ((u64)e1 << 32);
      }
    }
  } else {
    gemm_core(Xp + (size_t)st * 131072, Wp + (size_t)dt * 131072, acc);
#pragma unroll
    for (int i = 0; i < 4; i++) {
      const int s0 = st * 128 + amr + i * 16 + lk * 4;
      const int b_ = s0 >> 10, si = s0 & 1023;
      const int sblk = si >> 3, soff = si & 7;
#pragma unroll
      for (int j = 0; j < 4; j++) {
        const int d = dt * 128 + bnr + j * 16 + lr;
        const int h = d >> 6, dd = d & 63;
        const float bb = bias[d];
        u32 e0 = pkbf(acc[i][j][0] + bb, acc[i][j][1] + bb);
        u32 e1 = pkbf(acc[i][j][2] + bb, acc[i][j][3] + bb);
        *(u64*)(V4 + (size_t)(b_ * 16 + h) * 65536 +
                (size_t)(sblk * 64 + dd) * 8 + soff) =
            (u64)e0 | ((u64)e1 << 32);
      }
    }
  }
}

// ---------------- output projection ----------------
__global__ __launch_bounds__(256) void k_oproj(const u16* __restrict__ Xb,
                                               const u16* __restrict__ Wob,
                                               float* __restrict__ Out) {
  const int bid0 = blockIdx.x;
  const int bid = (bid0 & 7) * 32 + (bid0 >> 3);  // XCD swizzle (256%8==0)
  const int mb = bid >> 3, nb = bid & 7;
  f32x4 acc[4][4] = {};
  gemm_core(Xb + (size_t)mb * 131072, Wob + (size_t)nb * 131072, acc);
  const int t = threadIdx.x;
  const int l = t & 63, w = t >> 6, lr = l & 15, lk = l >> 4;
  const int amr = (w & 1) * 64, bnr = (w >> 1) * 64;
#pragma unroll
  for (int i = 0; i < 4; i++)
#pragma unroll
    for (int j = 0; j < 4; j++)
#pragma unroll
      for (int r = 0; r < 4; r++) {
        const int m = mb * 128 + amr + i * 16 + lk * 4 + r;
        const int n = nb * 128 + bnr + j * 16 + lr;
        Out[(size_t)m * 1024 + n] = acc[i][j][r];
      }
}

// ------- flash attention: 32x32 MFMA, LDS-staged, SPLIT-K ------------------
// Block = 4 waves: (wq = w&1 q-group) x (kh = w>>1 key-half). qtile 64,
// grid 1024 (4 blocks/CU; LDS 32KB single-buffer). Staging amortizes the
// vector-memory pipe 4x (R8-R11 lesson: per-wave L2 fragment loads are
// TA/L1-issue-bound); split-K halves the serial chain and doubles TLP vs R7.
// Per step: barrier -> stage both halves' tiles (8 gload_lds/thread) ->
// barrier(drain) -> compute. Fragment math / softmax / permlane identical
// to the R11-verified path. Split-K combine (R11-verified) reuses the dead
// K/V LDS after a barrier.
__global__ __launch_bounds__(256, 4) void k_attn(const u16* __restrict__ Qb,
                                                 const u16* __restrict__ Kb,
                                                 const u16* __restrict__ V4,
                                                 const u64* __restrict__ MB,
                                                 u16* __restrict__ xbuf) {
  __shared__ __attribute__((aligned(16))) u16 SMEM[16384];  // 32 KB
  // layout: K half kh at SMEM + kh*4096 (8KB each);
  //         V half kh at SMEM + 8192 + kh*4096; combine reuses SMEM as f32.
  const int t = threadIdx.x, l = t & 63, w = t >> 6;  // w in 0..3
  const int q5 = l & 31, hi = l >> 5;
  const int wq = w & 1;   // q-group within block
  const int kh = w >> 1;  // key-half: 0 -> tiles 0..7, 1 -> tiles 8..15
  const int bid = (blockIdx.x & 7) * 128 + (blockIdx.x >> 3);  // XCD swizzle
  const int qt = bid & 15, hb = bid >> 4;
  const int h = hb >> 2, b = hb & 3;
  const int s0 = qt * 64;
  const u16* Qhb = Qb + (size_t)(b * 16 + h) * 65536;
  const u16* Khb = Kb + (size_t)(b * 16 + h) * 65536;
  const u16* Vhb = V4 + (size_t)(b * 16 + h) * 65536;
  const int q = s0 + wq * 32 + q5;  // this lane's q (output column)
  const u64* MBq = MB + ((size_t)b * 1024 + q) * 16;
  const int kt0 = kh * 8;

  // Q fragments (B-operand of 32x32x16): lane holds Q[q][ds*16 + hi*8 ..+7]
  s16x8 qf[4];
#pragma unroll
  for (int ds = 0; ds < 4; ds++)
    qf[ds] = *(const s16x8*)(Qhb + (size_t)q * 64 + ds * 16 + hi * 8);

  f32x16 xa0 = {}, xa1 = {};  // out^T rows d: xa0 d=0..31, xa1 d=32..63
  float ls = 0.f, m_ = -__builtin_inff();

  // staging geometry (pre-swizzled global source, linear LDS dest) — per half
  const int ca = t, cb_ = t + 256;
  const int rA = ca >> 3, colA = (ca & 7) * 16;
  const int rB = cb_ >> 3, colB = (cb_ & 7) * 16;
  const int sA = colA ^ ((rA & 7) << 4);
  const int sB = colB ^ ((rB & 7) << 4);
  const u16* KgA = Khb + (size_t)rA * 64 + (sA >> 1);
  const u16* KgB = Khb + (size_t)rB * 64 + (sB >> 1);
  const u16* VgA = Vhb + (size_t)(sA >> 4) * 512 + rA * 8;
  const u16* VgB = Vhb + (size_t)(sB >> 4) * 512 + rB * 8;

  // per-lane read base: row q5 (keys for K / d for V), col hi*16, XOR-swizzled
  const int rbase = q5 * 128 + ((hi * 16) ^ ((q5 & 7) << 4));
  const char* Kc = (const char*)(SMEM + kh * 4096);
  const char* Vc = (const char*)(SMEM + 8192 + kh * 4096);

  u64 mw = MBq[kt0];
  for (int i = 0; i < 8; i++) {
    if (i > 0) __syncthreads();  // prev compute done reading LDS
    {  // stage this step's tiles for BOTH halves (tile i and tile 8+i)
      const int o0 = i * 4096, o1 = (8 + i) * 4096;
      GLOAD_LDS16(KgA + o0, &SMEM[ca * 8]);
      GLOAD_LDS16(KgB + o0, &SMEM[cb_ * 8]);
      GLOAD_LDS16(KgA + o1, &SMEM[4096 + ca * 8]);
      GLOAD_LDS16(KgB + o1, &SMEM[4096 + cb_ * 8]);
      GLOAD_LDS16(VgA + o0, &SMEM[8192 + ca * 8]);
      GLOAD_LDS16(VgB + o0, &SMEM[8192 + cb_ * 8]);
      GLOAD_LDS16(VgA + o1, &SMEM[12288 + ca * 8]);
      GLOAD_LDS16(VgB + o1, &SMEM[12288 + cb_ * 8]);
    }
    __syncthreads();  // drain staging (vmcnt0) -> tiles visible
    const u64 nw = MBq[kt0 + ((i + 1) & 7)];  // prefetch next mask word

    // QK^T: z0 = keys +0..31, z1 = keys +32..63 (rows), cols = q
    f32x16 z0 = {}, z1 = {};
#pragma unroll
    for (int ds = 0; ds < 4; ds++) {
      s16x8 k0 = *(const s16x8*)(Kc + (rbase ^ (ds * 32)));
      s16x8 k1 = *(const s16x8*)(Kc + 4096 + (rbase ^ (ds * 32)));
      __builtin_amdgcn_s_setprio(1);
      z0 = mfma32x32(k0, qf[ds], z0);
      z1 = mfma32x32(k1, qf[ds], z1);
      __builtin_amdgcn_s_setprio(0);
    }

    // exact online max (4 parallel chains, no temp array)
    float t0 = fmaxf(z0[0], z1[0]), t1 = fmaxf(z0[1], z1[1]);
    float t2 = fmaxf(z0[2], z1[2]), t3 = fmaxf(z0[3], z1[3]);
#pragma unroll
    for (int r = 4; r < 16; r += 4) {
      t0 = fmaxf(t0, fmaxf(z0[r], z1[r]));
      t1 = fmaxf(t1, fmaxf(z0[r + 1], z1[r + 1]));
      t2 = fmaxf(t2, fmaxf(z0[r + 2], z1[r + 2]));
      t3 = fmaxf(t3, fmaxf(z0[r + 3], z1[r + 3]));
    }
    float tm = fmaxf(fmaxf(t0, t1), fmaxf(t2, t3));
    tm = fmaxf(tm, __shfl_xor(tm, 32));  // share across (q,hi) pair
    if (tm > m_) {
      const float scl = ex2(m_ - tm);  // ex2(-inf)=0 on first tile
      m_ = tm;
      ls *= scl;
      xa0 *= scl;
      xa1 *= scl;
    }

    // exp2 IN-PLACE: z := 2^(z - m), max-normalized (P in (0,1])
#pragma unroll
    for (int r = 0; r < 16; r++) z0[r] = ex2(z0[r] - m_);
#pragma unroll
    for (int r = 0; r < 16; r++) z1[r] = ex2(z1[r] - m_);
    if (!__all(mw == ~0ull)) {  // mask is ~always all-pass; slow path exact
      const u32 mh0 = (u32)(mw >> (hi * 4));
      const u32 mh1 = (u32)(mw >> (hi * 4 + 32));
#pragma unroll
      for (int r = 0; r < 16; r++) {
        const int bp = 8 * (r >> 2) + (r & 3);
        z0[r] = ((mh0 >> bp) & 1u) ? z0[r] : 0.f;
        z1[r] = ((mh1 >> bp) & 1u) ? z1[r] : 0.f;
      }
    }
    float ts = 0.f;
#pragma unroll
    for (int r = 0; r < 16; r++) ts += z0[r] + z1[r];
    ls += ts;

    // pack quads to bf16 pairs directly from z:
    // P0[blk][qi] = keys(blk*32 + 8qi + 4hi + {0,1}), P1: {2,3}
    u32 P0[2][4], P1[2][4];
#pragma unroll
    for (int qi = 0; qi < 4; qi++) {
      P0[0][qi] = pkbf(z0[4 * qi], z0[4 * qi + 1]);
      P1[0][qi] = pkbf(z0[4 * qi + 2], z0[4 * qi + 3]);
      P0[1][qi] = pkbf(z1[4 * qi], z1[4 * qi + 1]);
      P1[1][qi] = pkbf(z1[4 * qi + 2], z1[4 * qi + 3]);
    }

    // PV over 4 key-slices; B-frag via permlane32_swap (a.HI <-> b.LO):
    // swap(P0[kb][qi0], P0[kb][qi1]) -> (word0, word2)
    // swap(P1[kb][qi0], P1[kb][qi1]) -> (word1, word3)
    // word j then holds keys ks*16 + hi*8 + {2j, 2j+1} for col q5.
#pragma unroll
    for (int ks = 0; ks < 4; ks++) {
      const int kb_ = ks >> 1, qi0 = (ks & 1) * 2, qi1 = qi0 + 1;
      u32 w0 = P0[kb_][qi0], w2 = P0[kb_][qi1];
      u32 w1 = P1[kb_][qi0], w3 = P1[kb_][qi1];
      asm("v_permlane32_swap_b32 %0, %1" : "+v"(w0), "+v"(w2));
      asm("v_permlane32_swap_b32 %0, %1" : "+v"(w1), "+v"(w3));
      u32x4 fv;
      fv[0] = w0; fv[1] = w1; fv[2] = w2; fv[3] = w3;
      const s16x8 pb = __builtin_bit_cast(s16x8, fv);
      s16x8 v0 = *(const s16x8*)(Vc + (rbase ^ (ks * 32)));
      s16x8 v1 = *(const s16x8*)(Vc + 4096 + (rbase ^ (ks * 32)));
      __builtin_amdgcn_s_setprio(1);
      xa0 = mfma32x32(v0, pb, xa0);
      xa1 = mfma32x32(v1, pb, xa1);
      __builtin_amdgcn_s_setprio(0);
    }
    mw = nw;
  }

  // ---- split-K combine (reuses dead K/V LDS): waves 2,3 publish; 0,1 merge
  float* cmb = (float*)SMEM;
  __syncthreads();  // all LDS tile reads done before overwrite
  if (w >= 2) {
    float* p = &cmb[(size_t)((w - 2) * 64 + l) * 36];
    *(f32x16*)(p) = xa0;
    *(f32x16*)(p + 16) = xa1;
    p[32] = m_;
    p[33] = ls;
  }
  __syncthreads();
  if (w >= 2) return;
  {
    const float* p = &cmb[(size_t)(wq * 64 + l) * 36];
    const f32x16 xb0 = *(const f32x16*)(p);
    const f32x16 xb1 = *(const f32x16*)(p + 16);
    const float mb = p[32], lsb = p[33];
    const float m = fmaxf(m_, mb);
    const float sa = ex2(m_ - m), sb = ex2(mb - m);
    ls = ls * sa + lsb * sb;
    xa0 = xa0 * sa + xb0 * sb;
    xa1 = xa1 * sa + xb1 * sb;
  }

  // epilogue: combine ls halves, normalize, write reference's mixed layout
  ls += __shfl_xor(ls, 32);
  const float inv = 1.0f / ls;
  const size_t rowb = (size_t)b * 1048576 + (size_t)(h * 64 + (q >> 4)) * 1024 +
                      (size_t)(q & 15) * 64;
#pragma unroll
  for (int qi = 0; qi < 4; qi++) {
    u32 a0 = pkbf(xa0[4 * qi] * inv, xa0[4 * qi + 1] * inv);
    u32 a1 = pkbf(xa0[4 * qi + 2] * inv, xa0[4 * qi + 3] * inv);
    *(u64*)(xbuf + rowb + 8 * qi + 4 * hi) = (u64)a0 | ((u64)a1 << 32);
    u32 b0 = pkbf(xa1[4 * qi] * inv, xa1[4 * qi + 1] * inv);
    u32 b1 = pkbf(xa1[4 * qi + 2] * inv, xa1[4 * qi + 3] * inv);
    *(u64*)(xbuf + rowb + 32 + 8 * qi + 4 * hi) = (u64)b0 | ((u64)b1 << 32);
  }
}

extern "C" void kernel_launch(void* const* d_in, const int* in_sizes, int n_in,
                              void* d_out, int out_size, void* d_ws,
                              size_t ws_size, hipStream_t stream) {
  const float* query = (const float*)d_in[0];
  const float* key_ = (const float*)d_in[1];
  const float* value = (const float*)d_in[2];
  const float* mask = (const float*)d_in[3];
  const float* bq = (const float*)d_in[5];
  const float* bk = (const float*)d_in[7];
  const float* bv = (const float*)d_in[9];
  const float* Wq = (const float*)d_in[4];
  const float* Wk = (const float*)d_in[6];
  const float* Wv = (const float*)d_in[8];
  const float* Wo = (const float*)d_in[10];

  char* ws = (char*)d_ws;
  u16* Xq = (u16*)(ws + 0 * WSMB);   // reused as xbuf after QKV GEMM
  u16* Xk = (u16*)(ws + 8 * WSMB);   // reused as MB after QKV GEMM
  u16* Xv = (u16*)(ws + 16 * WSMB);
  u16* Wqb = (u16*)(ws + 24 * WSMB);
  u16* Wkb = (u16*)(ws + 26 * WSMB);
  u16* Wvb = (u16*)(ws + 28 * WSMB);
  u16* Wob = (u16*)(ws + 30 * WSMB);
  u16* Qb = (u16*)(ws + 32 * WSMB);
  u16* Kb = (u16*)(ws + 40 * WSMB);
  u16* V4 = (u16*)(ws + 48 * WSMB);
  u64* bits = (u64*)(ws + 56 * WSMB);
  u64* MBm = (u64*)(ws + 8 * WSMB);  // 512 KB, overlaps dead Xk
  u16* xbuf = Xq;

  k_prep<<<dim3(4096, 8), 256, 0, stream>>>(query, key_, value, Wq, Wk, Wv, Wo,
                                            mask, Xq, Xk, Xv, Wqb, Wkb, Wvb,
                                            Wob, bits);
  k_qkv<<<768, 256, 0, stream>>>(Xq, Xk, Xv, Wqb, Wkb, Wvb, bq, bk, bv, Qb, Kb,
                                 V4);
  k_mm<<<1024, 256, 0, stream>>>(bits, MBm);
  k_attn<<<1024, 256, 0, stream>>>(Qb, Kb, V4, MBm, xbuf);
  k_oproj<<<256, 256, 0, stream>>>(xbuf, Wob, (float*)d_out);
}

// Round 13
// 116.908 us; speedup vs baseline: 1.1927x; 1.1927x over previous
//
#include <hip/hip_runtime.h>

typedef unsigned int u32;
typedef unsigned short u16;
typedef unsigned long long u64;
typedef __attribute__((ext_vector_type(8))) short s16x8;
typedef __attribute__((ext_vector_type(8))) __bf16 bf16x8;
typedef __attribute__((ext_vector_type(4))) float f32x4;
typedef __attribute__((ext_vector_type(16))) float f32x16;
typedef __attribute__((ext_vector_type(4))) u32 u32x4;

#define WSMB (1ull << 20)
#define QSC 0.18033688011112042f  // log2(e)/8, folded into Q projection

static __device__ __forceinline__ u16 f2bf(float f) {
  u32 u = __builtin_bit_cast(u32, f);
  return (u16)((u + 0x7fffu + ((u >> 16) & 1u)) >> 16);
}

// v_cvt_pk_bf16_f32: low16 = bf16(lo), high16 = bf16(hi)  (RNE)
static __device__ __forceinline__ u32 pkbf(float lo, float hi) {
  u32 r;
  asm("v_cvt_pk_bf16_f32 %0, %1, %2" : "=v"(r) : "v"(lo), "v"(hi));
  return r;
}

// native exp2
static __device__ __forceinline__ float ex2(float x) {
  float r;
  asm("v_exp_f32 %0, %1" : "=v"(r) : "v"(x));
  return r;
}

static __device__ __forceinline__ f32x4 mfma16x16(s16x8 a, s16x8 b, f32x4 c) {
  return __builtin_amdgcn_mfma_f32_16x16x32_bf16(
      __builtin_bit_cast(bf16x8, a), __builtin_bit_cast(bf16x8, b), c, 0, 0, 0);
}

static __device__ __forceinline__ f32x16 mfma32x32(s16x8 a, s16x8 b, f32x16 c) {
  return __builtin_amdgcn_mfma_f32_32x32x16_bf16(
      __builtin_bit_cast(bf16x8, a), __builtin_bit_cast(bf16x8, b), c, 0, 0, 0);
}

#define GLOAD_LDS16(g, l)                                                      \
  __builtin_amdgcn_global_load_lds(                                            \
      (const __attribute__((address_space(1))) u32*)(const void*)(g),          \
      (__attribute__((address_space(3))) u32*)(void*)(l), 16, 0, 0)

// ------- merged fp32->bf16 converts + mask bitmask (one 2D launch) ---------
// y 0-2: X q/k/v (4096 blocks); y 3-6: weights (1024 blocks); y 7: bits.
__global__ __launch_bounds__(256) void k_prep(
    const float* __restrict__ xq, const float* __restrict__ xk,
    const float* __restrict__ xv, const float* __restrict__ wq,
    const float* __restrict__ wk, const float* __restrict__ wv,
    const float* __restrict__ wo, const float* __restrict__ mask,
    u16* __restrict__ oxq, u16* __restrict__ oxk, u16* __restrict__ oxv,
    u16* __restrict__ owq, u16* __restrict__ owk, u16* __restrict__ owv,
    u16* __restrict__ owo, u64* __restrict__ bits) {
  const int y = blockIdx.y;
  if (y >= 3 && blockIdx.x >= 1024) return;
  if (y == 7) {  // mask -> 64-bit row bitmasks
    int w = threadIdx.x >> 6, l = threadIdx.x & 63;
    int r = blockIdx.x * 4 + w;
    float v = mask[(size_t)r * 64 + l];
    u64 bl = __ballot(v != 0.0f);
    if (l == 0) bits[r] = bl;
    return;
  }
  const float* s;
  u16* d;
  switch (y) {
    case 0: s = xq; d = oxq; break;
    case 1: s = xk; d = oxk; break;
    case 2: s = xv; d = oxv; break;
    case 3: s = wq; d = owq; break;
    case 4: s = wk; d = owk; break;
    case 5: s = wv; d = owv; break;
    default: s = wo; d = owo; break;
  }
  int i = (blockIdx.x * 256 + threadIdx.x) * 4;
  float4 v = *(const float4*)(s + i);
  u64 p = (u64)f2bf(v.x) | ((u64)f2bf(v.y) << 16) | ((u64)f2bf(v.z) << 32) |
          ((u64)f2bf(v.w) << 48);
  *(u64*)(d + i) = p;
}

// ---------------- mask bit-matrix: MB[qg][kt] bit j = row qg visible key kt*64+j
__global__ __launch_bounds__(256) void k_mm(const u64* __restrict__ bits,
                                            u64* __restrict__ MB) {
  int wv = threadIdx.x >> 6, l = threadIdx.x & 63;
  int qg = blockIdx.x * 4 + wv;  // 0..4095
  u64 bq = bits[qg];
  const u64* bb = bits + (qg & ~1023);
  u64* out = MB + (size_t)qg * 16;
  for (int kt = 0; kt < 16; kt++) {
    u64 bk = bb[kt * 64 + l];
    u64 m = __ballot((bq & bk) != 0ull);
    if (l == 0) out[kt] = m;
  }
}

// ------- shared GEMM core: C[128x128] = A[128xK] * B[128xK]^T --------------
static __device__ __forceinline__ void gemm_core(const u16* __restrict__ A,
                                                 const u16* __restrict__ Bw,
                                                 f32x4 (&acc)[4][4]) {
  __shared__ __attribute__((aligned(16))) u16 As[2][4096];
  __shared__ __attribute__((aligned(16))) u16 Bs[2][4096];
  const int t = threadIdx.x;
  const int l = t & 63, w = t >> 6, lr = l & 15, lk = l >> 4;
  const int amr = (w & 1) * 64, bnr = (w >> 1) * 64;
  const int c0 = t, c1 = t + 256;
  const int r0 = c0 >> 2, r1 = c1 >> 2;
  const int sw0 = ((c0 & 3) * 8) ^ ((r0 & 6) << 2);  // element offset in row
  const int sw1 = ((c1 & 3) * 8) ^ ((r1 & 6) << 2);
  const u16* Ag0 = A + (size_t)r0 * 1024 + sw0;
  const u16* Ag1 = A + (size_t)r1 * 1024 + sw1;
  const u16* Bg0 = Bw + (size_t)r0 * 1024 + sw0;
  const u16* Bg1 = Bw + (size_t)r1 * 1024 + sw1;
  const int aswz = (lk * 16) ^ ((lr & 6) << 3);  // byte offset in 64B row

  GLOAD_LDS16(Ag0, &As[0][c0 * 8]);
  GLOAD_LDS16(Ag1, &As[0][c1 * 8]);
  GLOAD_LDS16(Bg0, &Bs[0][c0 * 8]);
  GLOAD_LDS16(Bg1, &Bs[0][c1 * 8]);

  int cur = 0;
  for (int kt = 0; kt < 1024; kt += 32) {
    __syncthreads();  // drains cur loads + prev-iter LDS reads
    if (kt < 992) {
      const int nxt = cur ^ 1;
      GLOAD_LDS16(Ag0 + kt + 32, &As[nxt][c0 * 8]);
      GLOAD_LDS16(Ag1 + kt + 32, &As[nxt][c1 * 8]);
      GLOAD_LDS16(Bg0 + kt + 32, &Bs[nxt][c0 * 8]);
      GLOAD_LDS16(Bg1 + kt + 32, &Bs[nxt][c1 * 8]);
    }
    const char* Ac = (const char*)As[cur];
    const char* Bc = (const char*)Bs[cur];
    s16x8 af[4], bf[4];
#pragma unroll
    for (int i = 0; i < 4; i++)
      af[i] = *(const s16x8*)(Ac + (amr + i * 16 + lr) * 64 + aswz);
#pragma unroll
    for (int j = 0; j < 4; j++)
      bf[j] = *(const s16x8*)(Bc + (bnr + j * 16 + lr) * 64 + aswz);
    __builtin_amdgcn_s_setprio(1);
#pragma unroll
    for (int i = 0; i < 4; i++)
#pragma unroll
      for (int j = 0; j < 4; j++)
        acc[i][j] = mfma16x16(af[i], bf[j], acc[i][j]);
    __builtin_amdgcn_s_setprio(0);
    cur ^= 1;
  }
}

// ---------------- fused QKV projection ----------------
// Q/K: C^T orientation (rows=d, cols=s) -> packed b64 stores to [b,h][s][d].
// Q additionally scaled by QSC = log2(e)/8 (attn uses exp2 domain).
// V:   C orientation -> blocked V4[b,h][s>>3][d][s&7].
__global__ __launch_bounds__(256) void k_qkv(
    const u16* __restrict__ Xq, const u16* __restrict__ Xk,
    const u16* __restrict__ Xv, const u16* __restrict__ Wqb,
    const u16* __restrict__ Wkb, const u16* __restrict__ Wvb,
    const float* __restrict__ bq, const float* __restrict__ bk,
    const float* __restrict__ bv, u16* __restrict__ Qo, u16* __restrict__ Ko,
    u16* __restrict__ V4) {
  const int bid0 = blockIdx.x;
  const int bid = (bid0 & 7) * 96 + (bid0 >> 3);  // XCD swizzle (768%8==0)
  const int proj = bid >> 8;
  const int rem = bid & 255;
  const int st = rem >> 3, dt = rem & 7;
  const u16* Xp = proj == 0 ? Xq : (proj == 1 ? Xk : Xv);
  const u16* Wp = proj == 0 ? Wqb : (proj == 1 ? Wkb : Wvb);
  const float* bias = proj == 0 ? bq : (proj == 1 ? bk : bv);
  const int t = threadIdx.x;
  const int l = t & 63, w = t >> 6, lr = l & 15, lk = l >> 4;
  const int amr = (w & 1) * 64, bnr = (w >> 1) * 64;
  f32x4 acc[4][4] = {};
  if (proj < 2) {
    const float sc = proj == 0 ? QSC : 1.0f;
    gemm_core(Wp + (size_t)dt * 131072, Xp + (size_t)st * 131072, acc);
    u16* O = proj ? Ko : Qo;
#pragma unroll
    for (int i = 0; i < 4; i++) {
      const int d0 = dt * 128 + amr + i * 16 + lk * 4;
      const int h = d0 >> 6, dd0 = d0 & 63;
      const float4 b4 = *(const float4*)(bias + d0);
#pragma unroll
      for (int j = 0; j < 4; j++) {
        const int s = st * 128 + bnr + j * 16 + lr;
        const int b_ = s >> 10, si = s & 1023;
        u32 e0 = pkbf((acc[i][j][0] + b4.x) * sc, (acc[i][j][1] + b4.y) * sc);
        u32 e1 = pkbf((acc[i][j][2] + b4.z) * sc, (acc[i][j][3] + b4.w) * sc);
        *(u64*)(O + ((size_t)((b_ * 16 + h) * 1024 + si)) * 64 + dd0) =
            (u64)e0 | ((u64)e1 << 32);
      }
    }
  } else {
    gemm_core(Xp + (size_t)st * 131072, Wp + (size_t)dt * 131072, acc);
#pragma unroll
    for (int i = 0; i < 4; i++) {
      const int s0 = st * 128 + amr + i * 16 + lk * 4;
      const int b_ = s0 >> 10, si = s0 & 1023;
      const int sblk = si >> 3, soff = si & 7;
#pragma unroll
      for (int j = 0; j < 4; j++) {
        const int d = dt * 128 + bnr + j * 16 + lr;
        const int h = d >> 6, dd = d & 63;
        const float bb = bias[d];
        u32 e0 = pkbf(acc[i][j][0] + bb, acc[i][j][1] + bb);
        u32 e1 = pkbf(acc[i][j][2] + bb, acc[i][j][3] + bb);
        *(u64*)(V4 + (size_t)(b_ * 16 + h) * 65536 +
                (size_t)(sblk * 64 + dd) * 8 + soff) =
            (u64)e0 | ((u64)e1 << 32);
      }
    }
  }
}

// ---------------- output projection ----------------
__global__ __launch_bounds__(256) void k_oproj(const u16* __restrict__ Xb,
                                               const u16* __restrict__ Wob,
                                               float* __restrict__ Out) {
  const int bid0 = blockIdx.x;
  const int bid = (bid0 & 7) * 32 + (bid0 >> 3);  // XCD swizzle (256%8==0)
  const int mb = bid >> 3, nb = bid & 7;
  f32x4 acc[4][4] = {};
  gemm_core(Xb + (size_t)mb * 131072, Wob + (size_t)nb * 131072, acc);
  const int t = threadIdx.x;
  const int l = t & 63, w = t >> 6, lr = l & 15, lk = l >> 4;
  const int amr = (w & 1) * 64, bnr = (w >> 1) * 64;
#pragma unroll
  for (int i = 0; i < 4; i++)
#pragma unroll
    for (int j = 0; j < 4; j++)
#pragma unroll
      for (int r = 0; r < 4; r++) {
        const int m = mb * 128 + amr + i * 16 + lk * 4 + r;
        const int n = nb * 128 + bnr + j * 16 + lr;
        Out[(size_t)m * 1024 + n] = acc[i][j][r];
      }
}

// ---------------- flash attention: 32x32 MFMA, in-register P ---------------
// R7-VERIFIED version (best measured: total 119.0 us). Wave owns 32 q
// (q = lane&31). QK^T: z = K*Q^T (rows=keys, cols=q). Softmax: EXACT online
// max (scl = 2^(m_old-m_new); tm shared across the (q,hi) pair via
// shfl_xor(32)). P lane<->lane+32 via v_permlane32_swap_b32 (a.HI <-> b.LO).
// Double-buffered 32KB LDS staging, grid 512, 4 waves x 32 q.
__global__ __launch_bounds__(256, 3) void k_attn(const u16* __restrict__ Qb,
                                                 const u16* __restrict__ Kb,
                                                 const u16* __restrict__ V4,
                                                 const u64* __restrict__ MB,
                                                 u16* __restrict__ xbuf) {
  __shared__ __attribute__((aligned(16))) u16 Ks[2][4096];
  __shared__ __attribute__((aligned(16))) u16 Vs[2][4096];
  const int t = threadIdx.x, l = t & 63, w = t >> 6;
  const int q5 = l & 31, hi = l >> 5;
  const int bid = (blockIdx.x & 7) * 64 + (blockIdx.x >> 3);  // XCD swizzle
  const int qt = bid & 7, hb = bid >> 3;
  const int h = hb >> 2, b = hb & 3;
  const int s0 = qt * 128;
  const u16* Qhb = Qb + (size_t)(b * 16 + h) * 65536;
  const u16* Khb = Kb + (size_t)(b * 16 + h) * 65536;
  const u16* Vhb = V4 + (size_t)(b * 16 + h) * 65536;
  const int q = s0 + w * 32 + q5;  // this lane's q (output column)
  const u64* MBq = MB + ((size_t)b * 1024 + q) * 16;

  // Q fragments (B-operand of 32x32x16): lane holds Q[q][ds*16 + hi*8 ..+7]
  s16x8 qf[4];
#pragma unroll
  for (int ds = 0; ds < 4; ds++)
    qf[ds] = *(const s16x8*)(Qhb + (size_t)q * 64 + ds * 16 + hi * 8);

  f32x16 xa0 = {}, xa1 = {};  // out^T rows d: xa0 d=0..31, xa1 d=32..63
  float ls = 0.f, m_ = -__builtin_inff();

  // staging geometry (pre-swizzled global source, linear LDS dest)
  const int ca = t, cb_ = t + 256;
  const int rA = ca >> 3, colA = (ca & 7) * 16;
  const int rB = cb_ >> 3, colB = (cb_ & 7) * 16;
  const int sA = colA ^ ((rA & 7) << 4);
  const int sB = colB ^ ((rB & 7) << 4);
  const u16* KgA = Khb + (size_t)rA * 64 + (sA >> 1);
  const u16* KgB = Khb + (size_t)rB * 64 + (sB >> 1);
  const u16* VgA = Vhb + (size_t)(sA >> 4) * 512 + rA * 8;
  const u16* VgB = Vhb + (size_t)(sB >> 4) * 512 + rB * 8;

  // per-lane read base: row q5 (keys for K / d for V), col hi*16, XOR-swizzled
  const int rbase = q5 * 128 + ((hi * 16) ^ ((q5 & 7) << 4));

  // prologue: stage tile 0; load tile-0 mask word
  GLOAD_LDS16(KgA, &Ks[0][ca * 8]);
  GLOAD_LDS16(KgB, &Ks[0][cb_ * 8]);
  GLOAD_LDS16(VgA, &Vs[0][ca * 8]);
  GLOAD_LDS16(VgB, &Vs[0][cb_ * 8]);
  u64 mw = MBq[0];

  int cur = 0;
  for (int kt = 0; kt < 16; kt++) {
    __syncthreads();  // drains cur-tile loads + prior compute
    if (kt < 15) {    // prefetch next tile into the other buffer
      const int nxt = cur ^ 1;
      GLOAD_LDS16(KgA + (kt + 1) * 4096, &Ks[nxt][ca * 8]);
      GLOAD_LDS16(KgB + (kt + 1) * 4096, &Ks[nxt][cb_ * 8]);
      GLOAD_LDS16(VgA + (kt + 1) * 4096, &Vs[nxt][ca * 8]);
      GLOAD_LDS16(VgB + (kt + 1) * 4096, &Vs[nxt][cb_ * 8]);
    }
    const u64 nw = MBq[(kt + 1) & 15];  // prefetch next mask word
    const char* Kc = (const char*)Ks[cur];
    const char* Vc = (const char*)Vs[cur];

    // QK^T: z0 = keys 0..31, z1 = keys 32..63 (rows), cols = q
    f32x16 z0 = {}, z1 = {};
#pragma unroll
    for (int ds = 0; ds < 4; ds++) {
      s16x8 k0 = *(const s16x8*)(Kc + (rbase ^ (ds * 32)));
      s16x8 k1 = *(const s16x8*)(Kc + 4096 + (rbase ^ (ds * 32)));
      __builtin_amdgcn_s_setprio(1);
      z0 = mfma32x32(k0, qf[ds], z0);
      z1 = mfma32x32(k1, qf[ds], z1);
      __builtin_amdgcn_s_setprio(0);
    }

    // exact online max over this tile's 64 keys for lane's q
    float tmx[16];
#pragma unroll
    for (int r = 0; r < 16; r++) tmx[r] = fmaxf(z0[r], z1[r]);
#pragma unroll
    for (int st_ = 8; st_ >= 1; st_ >>= 1)
#pragma unroll
      for (int r = 0; r < 8; r++)
        if (r < st_) tmx[r] = fmaxf(tmx[r], tmx[r + st_]);
    float tm = tmx[0];
    tm = fmaxf(tm, __shfl_xor(tm, 32));  // share across (q,hi) pair
    if (tm > m_) {
      const float scl = ex2(m_ - tm);  // ex2(-inf)=0 on first tile
      m_ = tm;
      ls *= scl;
      xa0 *= scl;
      xa1 *= scl;
    }

    // e = 2^(z - m), max-normalized (P in (0,1])
    float e0[16], e1[16];
#pragma unroll
    for (int r = 0; r < 16; r++) e0[r] = ex2(z0[r] - m_);
#pragma unroll
    for (int r = 0; r < 16; r++) e1[r] = ex2(z1[r] - m_);
    if (!__all(mw == ~0ull)) {  // mask is ~always all-pass; slow path exact
      const u32 mh0 = (u32)(mw >> (hi * 4));
      const u32 mh1 = (u32)(mw >> (hi * 4 + 32));
#pragma unroll
      for (int r = 0; r < 16; r++) {
        const int bp = 8 * (r >> 2) + (r & 3);
        e0[r] = ((mh0 >> bp) & 1u) ? e0[r] : 0.f;
        e1[r] = ((mh1 >> bp) & 1u) ? e1[r] : 0.f;
      }
    }
    float ts = 0.f;
#pragma unroll
    for (int r = 0; r < 16; r++) ts += e0[r] + e1[r];
    ls += ts;

    // pack quads to bf16 pairs:
    // P0[blk][qi] = keys(blk*32 + 8qi + 4hi + {0,1}), P1: {2,3}
    u32 P0[2][4], P1[2][4];
#pragma unroll
    for (int qi = 0; qi < 4; qi++) {
      P0[0][qi] = pkbf(e0[4 * qi], e0[4 * qi + 1]);
      P1[0][qi] = pkbf(e0[4 * qi + 2], e0[4 * qi + 3]);
      P0[1][qi] = pkbf(e1[4 * qi], e1[4 * qi + 1]);
      P1[1][qi] = pkbf(e1[4 * qi + 2], e1[4 * qi + 3]);
    }

    // PV over 4 key-slices; B-frag via permlane32_swap (a.HI <-> b.LO):
    // swap(P0[kb][qi0], P0[kb][qi1]) -> (word0, word2)
    // swap(P1[kb][qi0], P1[kb][qi1]) -> (word1, word3)
    // word j then holds keys ks*16 + hi*8 + {2j, 2j+1} for col q5.
#pragma unroll
    for (int ks = 0; ks < 4; ks++) {
      const int kb = ks >> 1, qi0 = (ks & 1) * 2, qi1 = qi0 + 1;
      u32 w0 = P0[kb][qi0], w2 = P0[kb][qi1];
      u32 w1 = P1[kb][qi0], w3 = P1[kb][qi1];
      asm("v_permlane32_swap_b32 %0, %1" : "+v"(w0), "+v"(w2));
      asm("v_permlane32_swap_b32 %0, %1" : "+v"(w1), "+v"(w3));
      u32x4 fv;
      fv[0] = w0; fv[1] = w1; fv[2] = w2; fv[3] = w3;
      const s16x8 pb = __builtin_bit_cast(s16x8, fv);
      s16x8 v0 = *(const s16x8*)(Vc + (rbase ^ (ks * 32)));
      s16x8 v1 = *(const s16x8*)(Vc + 4096 + (rbase ^ (ks * 32)));
      __builtin_amdgcn_s_setprio(1);
      xa0 = mfma32x32(v0, pb, xa0);
      xa1 = mfma32x32(v1, pb, xa1);
      __builtin_amdgcn_s_setprio(0);
    }
    mw = nw;
    cur ^= 1;
  }

  // epilogue: combine ls halves, normalize, write reference's mixed layout
  ls += __shfl_xor(ls, 32);
  const float inv = 1.0f / ls;
  const size_t rowb = (size_t)b * 1048576 + (size_t)(h * 64 + (q >> 4)) * 1024 +
                      (size_t)(q & 15) * 64;
#pragma unroll
  for (int qi = 0; qi < 4; qi++) {
    u32 a0 = pkbf(xa0[4 * qi] * inv, xa0[4 * qi + 1] * inv);
    u32 a1 = pkbf(xa0[4 * qi + 2] * inv, xa0[4 * qi + 3] * inv);
    *(u64*)(xbuf + rowb + 8 * qi + 4 * hi) = (u64)a0 | ((u64)a1 << 32);
    u32 b0 = pkbf(xa1[4 * qi] * inv, xa1[4 * qi + 1] * inv);
    u32 b1 = pkbf(xa1[4 * qi + 2] * inv, xa1[4 * qi + 3] * inv);
    *(u64*)(xbuf + rowb + 32 + 8 * qi + 4 * hi) = (u64)b0 | ((u64)b1 << 32);
  }
}

extern "C" void kernel_launch(void* const* d_in, const int* in_sizes, int n_in,
                              void* d_out, int out_size, void* d_ws,
                              size_t ws_size, hipStream_t stream) {
  const float* query = (const float*)d_in[0];
  const float* key_ = (const float*)d_in[1];
  const float* value = (const float*)d_in[2];
  const float* mask = (const float*)d_in[3];
  const float* bq = (const float*)d_in[5];
  const float* bk = (const float*)d_in[7];
  const float* bv = (const float*)d_in[9];
  const float* Wq = (const float*)d_in[4];
  const float* Wk = (const float*)d_in[6];
  const float* Wv = (const float*)d_in[8];
  const float* Wo = (const float*)d_in[10];

  char* ws = (char*)d_ws;
  u16* Xq = (u16*)(ws + 0 * WSMB);   // reused as xbuf after QKV GEMM
  u16* Xk = (u16*)(ws + 8 * WSMB);   // reused as MB after QKV GEMM
  u16* Xv = (u16*)(ws + 16 * WSMB);
  u16* Wqb = (u16*)(ws + 24 * WSMB);
  u16* Wkb = (u16*)(ws + 26 * WSMB);
  u16* Wvb = (u16*)(ws + 28 * WSMB);
  u16* Wob = (u16*)(ws + 30 * WSMB);
  u16* Qb = (u16*)(ws + 32 * WSMB);
  u16* Kb = (u16*)(ws + 40 * WSMB);
  u16* V4 = (u16*)(ws + 48 * WSMB);
  u64* bits = (u64*)(ws + 56 * WSMB);
  u64* MBm = (u64*)(ws + 8 * WSMB);  // 512 KB, overlaps dead Xk
  u16* xbuf = Xq;

  k_prep<<<dim3(4096, 8), 256, 0, stream>>>(query, key_, value, Wq, Wk, Wv, Wo,
                                            mask, Xq, Xk, Xv, Wqb, Wkb, Wvb,
                                            Wob, bits);
  k_qkv<<<768, 256, 0, stream>>>(Xq, Xk, Xv, Wqb, Wkb, Wvb, bq, bk, bv, Qb, Kb,
                                 V4);
  k_mm<<<1024, 256, 0, stream>>>(bits, MBm);
  k_attn<<<512, 256, 0, stream>>>(Qb, Kb, V4, MBm, xbuf);
  k_oproj<<<256, 256, 0, stream>>>(xbuf, Wob, (float*)d_out);
}

// Round 14
// 114.913 us; speedup vs baseline: 1.2134x; 1.0174x over previous
//
#include <hip/hip_runtime.h>

typedef unsigned int u32;
typedef unsigned short u16;
typedef unsigned long long u64;
typedef __attribute__((ext_vector_type(8))) short s16x8;
typedef __attribute__((ext_vector_type(8))) __bf16 bf16x8;
typedef __attribute__((ext_vector_type(4))) float f32x4;
typedef __attribute__((ext_vector_type(16))) float f32x16;
typedef __attribute__((ext_vector_type(4))) u32 u32x4;

#define WSMB (1ull << 20)
#define QSC 0.18033688011112042f  // log2(e)/8, folded into Q projection

static __device__ __forceinline__ u16 f2bf(float f) {
  u32 u = __builtin_bit_cast(u32, f);
  return (u16)((u + 0x7fffu + ((u >> 16) & 1u)) >> 16);
}

// v_cvt_pk_bf16_f32: low16 = bf16(lo), high16 = bf16(hi)  (RNE)
static __device__ __forceinline__ u32 pkbf(float lo, float hi) {
  u32 r;
  asm("v_cvt_pk_bf16_f32 %0, %1, %2" : "=v"(r) : "v"(lo), "v"(hi));
  return r;
}

// native exp2
static __device__ __forceinline__ float ex2(float x) {
  float r;
  asm("v_exp_f32 %0, %1" : "=v"(r) : "v"(x));
  return r;
}

static __device__ __forceinline__ f32x4 mfma16x16(s16x8 a, s16x8 b, f32x4 c) {
  return __builtin_amdgcn_mfma_f32_16x16x32_bf16(
      __builtin_bit_cast(bf16x8, a), __builtin_bit_cast(bf16x8, b), c, 0, 0, 0);
}

static __device__ __forceinline__ f32x16 mfma32x32(s16x8 a, s16x8 b, f32x16 c) {
  return __builtin_amdgcn_mfma_f32_32x32x16_bf16(
      __builtin_bit_cast(bf16x8, a), __builtin_bit_cast(bf16x8, b), c, 0, 0, 0);
}

#define GLOAD_LDS16(g, l)                                                      \
  __builtin_amdgcn_global_load_lds(                                            \
      (const __attribute__((address_space(1))) u32*)(const void*)(g),          \
      (__attribute__((address_space(3))) u32*)(void*)(l), 16, 0, 0)

// ------- merged fp32->bf16 converts + mask bitmask (exact 1D grid) ---------
// blocks 0..12287: X q/k/v cvt; 12288..16383: W cvt; 16384..17407: bits.
__global__ __launch_bounds__(256) void k_prep(
    const float* __restrict__ xq, const float* __restrict__ xk,
    const float* __restrict__ xv, const float* __restrict__ wq,
    const float* __restrict__ wk, const float* __restrict__ wv,
    const float* __restrict__ wo, const float* __restrict__ mask,
    u16* __restrict__ oxq, u16* __restrict__ oxk, u16* __restrict__ oxv,
    u16* __restrict__ owq, u16* __restrict__ owk, u16* __restrict__ owv,
    u16* __restrict__ owo, u64* __restrict__ bits) {
  const int bid = blockIdx.x;
  if (bid >= 16384) {  // mask -> 64-bit row bitmasks
    int w = threadIdx.x >> 6, l = threadIdx.x & 63;
    int r = (bid - 16384) * 4 + w;
    float v = mask[(size_t)r * 64 + l];
    u64 bl = __ballot(v != 0.0f);
    if (l == 0) bits[r] = bl;
    return;
  }
  const float* s;
  u16* d;
  int x;
  if (bid < 12288) {
    const int y = bid >> 12;
    x = bid & 4095;
    if (y == 0) { s = xq; d = oxq; }
    else if (y == 1) { s = xk; d = oxk; }
    else { s = xv; d = oxv; }
  } else {
    const int y = (bid - 12288) >> 10;
    x = (bid - 12288) & 1023;
    if (y == 0) { s = wq; d = owq; }
    else if (y == 1) { s = wk; d = owk; }
    else if (y == 2) { s = wv; d = owv; }
    else { s = wo; d = owo; }
  }
  int i = (x * 256 + threadIdx.x) * 4;
  float4 v = *(const float4*)(s + i);
  u64 p = (u64)f2bf(v.x) | ((u64)f2bf(v.y) << 16) | ((u64)f2bf(v.z) << 32) |
          ((u64)f2bf(v.w) << 48);
  *(u64*)(d + i) = p;
}

// ------- shared GEMM core: C[128x128] = A[128xK] * B[128xK]^T --------------
static __device__ __forceinline__ void gemm_core(const u16* __restrict__ A,
                                                 const u16* __restrict__ Bw,
                                                 f32x4 (&acc)[4][4]) {
  __shared__ __attribute__((aligned(16))) u16 As[2][4096];
  __shared__ __attribute__((aligned(16))) u16 Bs[2][4096];
  const int t = threadIdx.x;
  const int l = t & 63, w = t >> 6, lr = l & 15, lk = l >> 4;
  const int amr = (w & 1) * 64, bnr = (w >> 1) * 64;
  const int c0 = t, c1 = t + 256;
  const int r0 = c0 >> 2, r1 = c1 >> 2;
  const int sw0 = ((c0 & 3) * 8) ^ ((r0 & 6) << 2);  // element offset in row
  const int sw1 = ((c1 & 3) * 8) ^ ((r1 & 6) << 2);
  const u16* Ag0 = A + (size_t)r0 * 1024 + sw0;
  const u16* Ag1 = A + (size_t)r1 * 1024 + sw1;
  const u16* Bg0 = Bw + (size_t)r0 * 1024 + sw0;
  const u16* Bg1 = Bw + (size_t)r1 * 1024 + sw1;
  const int aswz = (lk * 16) ^ ((lr & 6) << 3);  // byte offset in 64B row

  GLOAD_LDS16(Ag0, &As[0][c0 * 8]);
  GLOAD_LDS16(Ag1, &As[0][c1 * 8]);
  GLOAD_LDS16(Bg0, &Bs[0][c0 * 8]);
  GLOAD_LDS16(Bg1, &Bs[0][c1 * 8]);

  int cur = 0;
  for (int kt = 0; kt < 1024; kt += 32) {
    __syncthreads();  // drains cur loads + prev-iter LDS reads
    if (kt < 992) {
      const int nxt = cur ^ 1;
      GLOAD_LDS16(Ag0 + kt + 32, &As[nxt][c0 * 8]);
      GLOAD_LDS16(Ag1 + kt + 32, &As[nxt][c1 * 8]);
      GLOAD_LDS16(Bg0 + kt + 32, &Bs[nxt][c0 * 8]);
      GLOAD_LDS16(Bg1 + kt + 32, &Bs[nxt][c1 * 8]);
    }
    const char* Ac = (const char*)As[cur];
    const char* Bc = (const char*)Bs[cur];
    s16x8 af[4], bf[4];
#pragma unroll
    for (int i = 0; i < 4; i++)
      af[i] = *(const s16x8*)(Ac + (amr + i * 16 + lr) * 64 + aswz);
#pragma unroll
    for (int j = 0; j < 4; j++)
      bf[j] = *(const s16x8*)(Bc + (bnr + j * 16 + lr) * 64 + aswz);
    __builtin_amdgcn_s_setprio(1);
#pragma unroll
    for (int i = 0; i < 4; i++)
#pragma unroll
      for (int j = 0; j < 4; j++)
        acc[i][j] = mfma16x16(af[i], bf[j], acc[i][j]);
    __builtin_amdgcn_s_setprio(0);
    cur ^= 1;
  }
}

// ------- narrow GEMM core: C[128x64] = A[128xK] * B[64xK]^T ----------------
static __device__ __forceinline__ void gemm_core64(const u16* __restrict__ A,
                                                   const u16* __restrict__ Bw,
                                                   f32x4 (&acc)[4][2]) {
  __shared__ __attribute__((aligned(16))) u16 As[2][4096];
  __shared__ __attribute__((aligned(16))) u16 Bs[2][2048];
  const int t = threadIdx.x;
  const int l = t & 63, w = t >> 6, lr = l & 15, lk = l >> 4;
  const int amr = (w & 1) * 64, bnr = (w >> 1) * 32;
  const int c0 = t, c1 = t + 256;
  const int r0 = c0 >> 2, r1 = c1 >> 2;
  const int sw0 = ((c0 & 3) * 8) ^ ((r0 & 6) << 2);
  const int sw1 = ((c1 & 3) * 8) ^ ((r1 & 6) << 2);
  const u16* Ag0 = A + (size_t)r0 * 1024 + sw0;
  const u16* Ag1 = A + (size_t)r1 * 1024 + sw1;
  const u16* Bg0 = Bw + (size_t)r0 * 1024 + sw0;
  const int aswz = (lk * 16) ^ ((lr & 6) << 3);

  GLOAD_LDS16(Ag0, &As[0][c0 * 8]);
  GLOAD_LDS16(Ag1, &As[0][c1 * 8]);
  GLOAD_LDS16(Bg0, &Bs[0][c0 * 8]);

  int cur = 0;
  for (int kt = 0; kt < 1024; kt += 32) {
    __syncthreads();
    if (kt < 992) {
      const int nxt = cur ^ 1;
      GLOAD_LDS16(Ag0 + kt + 32, &As[nxt][c0 * 8]);
      GLOAD_LDS16(Ag1 + kt + 32, &As[nxt][c1 * 8]);
      GLOAD_LDS16(Bg0 + kt + 32, &Bs[nxt][c0 * 8]);
    }
    const char* Ac = (const char*)As[cur];
    const char* Bc = (const char*)Bs[cur];
    s16x8 af[4], bf[2];
#pragma unroll
    for (int i = 0; i < 4; i++)
      af[i] = *(const s16x8*)(Ac + (amr + i * 16 + lr) * 64 + aswz);
#pragma unroll
    for (int j = 0; j < 2; j++)
      bf[j] = *(const s16x8*)(Bc + (bnr + j * 16 + lr) * 64 + aswz);
    __builtin_amdgcn_s_setprio(1);
#pragma unroll
    for (int i = 0; i < 4; i++)
#pragma unroll
      for (int j = 0; j < 2; j++)
        acc[i][j] = mfma16x16(af[i], bf[j], acc[i][j]);
    __builtin_amdgcn_s_setprio(0);
    cur ^= 1;
  }
}

// ------- fused QKV projection + mask bit-matrix (merged grid 1792) ---------
// bid < 768: GEMM blocks (proj/st/dt as before, XCD-swizzled).
// bid >= 768: mask bit-matrix MB[qg][kt] (1024 blocks x 4 rows).
__global__ __launch_bounds__(256) void k_qkv(
    const u16* __restrict__ Xq, const u16* __restrict__ Xk,
    const u16* __restrict__ Xv, const u16* __restrict__ Wqb,
    const u16* __restrict__ Wkb, const u16* __restrict__ Wvb,
    const float* __restrict__ bq, const float* __restrict__ bk,
    const float* __restrict__ bv, u16* __restrict__ Qo, u16* __restrict__ Ko,
    u16* __restrict__ V4, const u64* __restrict__ bits,
    u64* __restrict__ MB) {
  const int bid0 = blockIdx.x;
  if (bid0 >= 768) {  // ---- mask bit-matrix path ----
    int wv = threadIdx.x >> 6, l = threadIdx.x & 63;
    int qg = (bid0 - 768) * 4 + wv;  // 0..4095
    u64 bqw = bits[qg];
    const u64* bb = bits + (qg & ~1023);
    u64* out = MB + (size_t)qg * 16;
    for (int kt = 0; kt < 16; kt++) {
      u64 bkw = bb[kt * 64 + l];
      u64 m = __ballot((bqw & bkw) != 0ull);
      if (l == 0) out[kt] = m;
    }
    return;
  }
  const int bid = (bid0 & 7) * 96 + (bid0 >> 3);  // XCD swizzle (768%8==0)
  const int proj = bid >> 8;
  const int rem = bid & 255;
  const int st = rem >> 3, dt = rem & 7;
  const u16* Xp = proj == 0 ? Xq : (proj == 1 ? Xk : Xv);
  const u16* Wp = proj == 0 ? Wqb : (proj == 1 ? Wkb : Wvb);
  const float* bias = proj == 0 ? bq : (proj == 1 ? bk : bv);
  const int t = threadIdx.x;
  const int l = t & 63, w = t >> 6, lr = l & 15, lk = l >> 4;
  const int amr = (w & 1) * 64, bnr = (w >> 1) * 64;
  f32x4 acc[4][4] = {};
  if (proj < 2) {
    const float sc = proj == 0 ? QSC : 1.0f;
    gemm_core(Wp + (size_t)dt * 131072, Xp + (size_t)st * 131072, acc);
    u16* O = proj ? Ko : Qo;
#pragma unroll
    for (int i = 0; i < 4; i++) {
      const int d0 = dt * 128 + amr + i * 16 + lk * 4;
      const int h = d0 >> 6, dd0 = d0 & 63;
      const float4 b4 = *(const float4*)(bias + d0);
#pragma unroll
      for (int j = 0; j < 4; j++) {
        const int s = st * 128 + bnr + j * 16 + lr;
        const int b_ = s >> 10, si = s & 1023;
        u32 e0 = pkbf((acc[i][j][0] + b4.x) * sc, (acc[i][j][1] + b4.y) * sc);
        u32 e1 = pkbf((acc[i][j][2] + b4.z) * sc, (acc[i][j][3] + b4.w) * sc);
        *(u64*)(O + ((size_t)((b_ * 16 + h) * 1024 + si)) * 64 + dd0) =
            (u64)e0 | ((u64)e1 << 32);
      }
    }
  } else {
    gemm_core(Xp + (size_t)st * 131072, Wp + (size_t)dt * 131072, acc);
#pragma unroll
    for (int i = 0; i < 4; i++) {
      const int s0 = st * 128 + amr + i * 16 + lk * 4;
      const int b_ = s0 >> 10, si = s0 & 1023;
      const int sblk = si >> 3, soff = si & 7;
#pragma unroll
      for (int j = 0; j < 4; j++) {
        const int d = dt * 128 + bnr + j * 16 + lr;
        const int h = d >> 6, dd = d & 63;
        const float bb = bias[d];
        u32 e0 = pkbf(acc[i][j][0] + bb, acc[i][j][1] + bb);
        u32 e1 = pkbf(acc[i][j][2] + bb, acc[i][j][3] + bb);
        *(u64*)(V4 + (size_t)(b_ * 16 + h) * 65536 +
                (size_t)(sblk * 64 + dd) * 8 + soff) =
            (u64)e0 | ((u64)e1 << 32);
      }
    }
  }
}

// ---------------- output projection: tile 128x64, grid 512 (2 blocks/CU) ---
__global__ __launch_bounds__(256) void k_oproj(const u16* __restrict__ Xb,
                                               const u16* __restrict__ Wob,
                                               float* __restrict__ Out) {
  const int bid0 = blockIdx.x;
  const int bid = (bid0 & 7) * 64 + (bid0 >> 3);  // XCD swizzle (512%8==0)
  const int mb = bid >> 4, nb = bid & 15;
  f32x4 acc[4][2] = {};
  gemm_core64(Xb + (size_t)mb * 131072, Wob + (size_t)nb * 65536, acc);
  const int t = threadIdx.x;
  const int l = t & 63, w = t >> 6, lr = l & 15, lk = l >> 4;
  const int amr = (w & 1) * 64, bnr = (w >> 1) * 32;
#pragma unroll
  for (int i = 0; i < 4; i++)
#pragma unroll
    for (int j = 0; j < 2; j++)
#pragma unroll
      for (int r = 0; r < 4; r++) {
        const int m = mb * 128 + amr + i * 16 + lk * 4 + r;
        const int n = nb * 64 + bnr + j * 16 + lr;
        Out[(size_t)m * 1024 + n] = acc[i][j][r];
      }
}

// ---------------- flash attention: 32x32 MFMA, in-register P ---------------
// R7-VERIFIED version (best measured). Wave owns 32 q (q = lane&31).
// QK^T: z = K*Q^T (rows=keys, cols=q). Softmax: EXACT online max.
// P lane<->lane+32 via v_permlane32_swap_b32 (a.HI <-> b.LO).
// Double-buffered 32KB LDS staging, grid 512, 4 waves x 32 q.
__global__ __launch_bounds__(256, 3) void k_attn(const u16* __restrict__ Qb,
                                                 const u16* __restrict__ Kb,
                                                 const u16* __restrict__ V4,
                                                 const u64* __restrict__ MB,
                                                 u16* __restrict__ xbuf) {
  __shared__ __attribute__((aligned(16))) u16 Ks[2][4096];
  __shared__ __attribute__((aligned(16))) u16 Vs[2][4096];
  const int t = threadIdx.x, l = t & 63, w = t >> 6;
  const int q5 = l & 31, hi = l >> 5;
  const int bid = (blockIdx.x & 7) * 64 + (blockIdx.x >> 3);  // XCD swizzle
  const int qt = bid & 7, hb = bid >> 3;
  const int h = hb >> 2, b = hb & 3;
  const int s0 = qt * 128;
  const u16* Qhb = Qb + (size_t)(b * 16 + h) * 65536;
  const u16* Khb = Kb + (size_t)(b * 16 + h) * 65536;
  const u16* Vhb = V4 + (size_t)(b * 16 + h) * 65536;
  const int q = s0 + w * 32 + q5;  // this lane's q (output column)
  const u64* MBq = MB + ((size_t)b * 1024 + q) * 16;

  // Q fragments (B-operand of 32x32x16): lane holds Q[q][ds*16 + hi*8 ..+7]
  s16x8 qf[4];
#pragma unroll
  for (int ds = 0; ds < 4; ds++)
    qf[ds] = *(const s16x8*)(Qhb + (size_t)q * 64 + ds * 16 + hi * 8);

  f32x16 xa0 = {}, xa1 = {};  // out^T rows d: xa0 d=0..31, xa1 d=32..63
  float ls = 0.f, m_ = -__builtin_inff();

  // staging geometry (pre-swizzled global source, linear LDS dest)
  const int ca = t, cb_ = t + 256;
  const int rA = ca >> 3, colA = (ca & 7) * 16;
  const int rB = cb_ >> 3, colB = (cb_ & 7) * 16;
  const int sA = colA ^ ((rA & 7) << 4);
  const int sB = colB ^ ((rB & 7) << 4);
  const u16* KgA = Khb + (size_t)rA * 64 + (sA >> 1);
  const u16* KgB = Khb + (size_t)rB * 64 + (sB >> 1);
  const u16* VgA = Vhb + (size_t)(sA >> 4) * 512 + rA * 8;
  const u16* VgB = Vhb + (size_t)(sB >> 4) * 512 + rB * 8;

  // per-lane read base: row q5 (keys for K / d for V), col hi*16, XOR-swizzled
  const int rbase = q5 * 128 + ((hi * 16) ^ ((q5 & 7) << 4));

  // prologue: stage tile 0; load tile-0 mask word
  GLOAD_LDS16(KgA, &Ks[0][ca * 8]);
  GLOAD_LDS16(KgB, &Ks[0][cb_ * 8]);
  GLOAD_LDS16(VgA, &Vs[0][ca * 8]);
  GLOAD_LDS16(VgB, &Vs[0][cb_ * 8]);
  u64 mw = MBq[0];

  int cur = 0;
  for (int kt = 0; kt < 16; kt++) {
    __syncthreads();  // drains cur-tile loads + prior compute
    if (kt < 15) {    // prefetch next tile into the other buffer
      const int nxt = cur ^ 1;
      GLOAD_LDS16(KgA + (kt + 1) * 4096, &Ks[nxt][ca * 8]);
      GLOAD_LDS16(KgB + (kt + 1) * 4096, &Ks[nxt][cb_ * 8]);
      GLOAD_LDS16(VgA + (kt + 1) * 4096, &Vs[nxt][ca * 8]);
      GLOAD_LDS16(VgB + (kt + 1) * 4096, &Vs[nxt][cb_ * 8]);
    }
    const u64 nw = MBq[(kt + 1) & 15];  // prefetch next mask word
    const char* Kc = (const char*)Ks[cur];
    const char* Vc = (const char*)Vs[cur];

    // QK^T: z0 = keys 0..31, z1 = keys 32..63 (rows), cols = q
    f32x16 z0 = {}, z1 = {};
#pragma unroll
    for (int ds = 0; ds < 4; ds++) {
      s16x8 k0 = *(const s16x8*)(Kc + (rbase ^ (ds * 32)));
      s16x8 k1 = *(const s16x8*)(Kc + 4096 + (rbase ^ (ds * 32)));
      __builtin_amdgcn_s_setprio(1);
      z0 = mfma32x32(k0, qf[ds], z0);
      z1 = mfma32x32(k1, qf[ds], z1);
      __builtin_amdgcn_s_setprio(0);
    }

    // exact online max over this tile's 64 keys for lane's q
    float tmx[16];
#pragma unroll
    for (int r = 0; r < 16; r++) tmx[r] = fmaxf(z0[r], z1[r]);
#pragma unroll
    for (int st_ = 8; st_ >= 1; st_ >>= 1)
#pragma unroll
      for (int r = 0; r < 8; r++)
        if (r < st_) tmx[r] = fmaxf(tmx[r], tmx[r + st_]);
    float tm = tmx[0];
    tm = fmaxf(tm, __shfl_xor(tm, 32));  // share across (q,hi) pair
    if (tm > m_) {
      const float scl = ex2(m_ - tm);  // ex2(-inf)=0 on first tile
      m_ = tm;
      ls *= scl;
      xa0 *= scl;
      xa1 *= scl;
    }

    // e = 2^(z - m), max-normalized (P in (0,1])
    float e0[16], e1[16];
#pragma unroll
    for (int r = 0; r < 16; r++) e0[r] = ex2(z0[r] - m_);
#pragma unroll
    for (int r = 0; r < 16; r++) e1[r] = ex2(z1[r] - m_);
    if (!__all(mw == ~0ull)) {  // mask is ~always all-pass; slow path exact
      const u32 mh0 = (u32)(mw >> (hi * 4));
      const u32 mh1 = (u32)(mw >> (hi * 4 + 32));
#pragma unroll
      for (int r = 0; r < 16; r++) {
        const int bp = 8 * (r >> 2) + (r & 3);
        e0[r] = ((mh0 >> bp) & 1u) ? e0[r] : 0.f;
        e1[r] = ((mh1 >> bp) & 1u) ? e1[r] : 0.f;
      }
    }
    float ts = 0.f;
#pragma unroll
    for (int r = 0; r < 16; r++) ts += e0[r] + e1[r];
    ls += ts;

    // pack quads to bf16 pairs:
    // P0[blk][qi] = keys(blk*32 + 8qi + 4hi + {0,1}), P1: {2,3}
    u32 P0[2][4], P1[2][4];
#pragma unroll
    for (int qi = 0; qi < 4; qi++) {
      P0[0][qi] = pkbf(e0[4 * qi], e0[4 * qi + 1]);
      P1[0][qi] = pkbf(e0[4 * qi + 2], e0[4 * qi + 3]);
      P0[1][qi] = pkbf(e1[4 * qi], e1[4 * qi + 1]);
      P1[1][qi] = pkbf(e1[4 * qi + 2], e1[4 * qi + 3]);
    }

    // PV over 4 key-slices; B-frag via permlane32_swap (a.HI <-> b.LO):
    // swap(P0[kb][qi0], P0[kb][qi1]) -> (word0, word2)
    // swap(P1[kb][qi0], P1[kb][qi1]) -> (word1, word3)
    // word j then holds keys ks*16 + hi*8 + {2j, 2j+1} for col q5.
#pragma unroll
    for (int ks = 0; ks < 4; ks++) {
      const int kb = ks >> 1, qi0 = (ks & 1) * 2, qi1 = qi0 + 1;
      u32 w0 = P0[kb][qi0], w2 = P0[kb][qi1];
      u32 w1 = P1[kb][qi0], w3 = P1[kb][qi1];
      asm("v_permlane32_swap_b32 %0, %1" : "+v"(w0), "+v"(w2));
      asm("v_permlane32_swap_b32 %0, %1" : "+v"(w1), "+v"(w3));
      u32x4 fv;
      fv[0] = w0; fv[1] = w1; fv[2] = w2; fv[3] = w3;
      const s16x8 pb = __builtin_bit_cast(s16x8, fv);
      s16x8 v0 = *(const s16x8*)(Vc + (rbase ^ (ks * 32)));
      s16x8 v1 = *(const s16x8*)(Vc + 4096 + (rbase ^ (ks * 32)));
      __builtin_amdgcn_s_setprio(1);
      xa0 = mfma32x32(v0, pb, xa0);
      xa1 = mfma32x32(v1, pb, xa1);
      __builtin_amdgcn_s_setprio(0);
    }
    mw = nw;
    cur ^= 1;
  }

  // epilogue: combine ls halves, normalize, write reference's mixed layout
  ls += __shfl_xor(ls, 32);
  const float inv = 1.0f / ls;
  const size_t rowb = (size_t)b * 1048576 + (size_t)(h * 64 + (q >> 4)) * 1024 +
                      (size_t)(q & 15) * 64;
#pragma unroll
  for (int qi = 0; qi < 4; qi++) {
    u32 a0 = pkbf(xa0[4 * qi] * inv, xa0[4 * qi + 1] * inv);
    u32 a1 = pkbf(xa0[4 * qi + 2] * inv, xa0[4 * qi + 3] * inv);
    *(u64*)(xbuf + rowb + 8 * qi + 4 * hi) = (u64)a0 | ((u64)a1 << 32);
    u32 b0 = pkbf(xa1[4 * qi] * inv, xa1[4 * qi + 1] * inv);
    u32 b1 = pkbf(xa1[4 * qi + 2] * inv, xa1[4 * qi + 3] * inv);
    *(u64*)(xbuf + rowb + 32 + 8 * qi + 4 * hi) = (u64)b0 | ((u64)b1 << 32);
  }
}

extern "C" void kernel_launch(void* const* d_in, const int* in_sizes, int n_in,
                              void* d_out, int out_size, void* d_ws,
                              size_t ws_size, hipStream_t stream) {
  const float* query = (const float*)d_in[0];
  const float* key_ = (const float*)d_in[1];
  const float* value = (const float*)d_in[2];
  const float* mask = (const float*)d_in[3];
  const float* bq = (const float*)d_in[5];
  const float* bk = (const float*)d_in[7];
  const float* bv = (const float*)d_in[9];
  const float* Wq = (const float*)d_in[4];
  const float* Wk = (const float*)d_in[6];
  const float* Wv = (const float*)d_in[8];
  const float* Wo = (const float*)d_in[10];

  char* ws = (char*)d_ws;
  u16* Xq = (u16*)(ws + 0 * WSMB);   // reused as xbuf after QKV GEMM
  u16* Xk = (u16*)(ws + 8 * WSMB);
  u16* Xv = (u16*)(ws + 16 * WSMB);
  u16* Wqb = (u16*)(ws + 24 * WSMB);
  u16* Wkb = (u16*)(ws + 26 * WSMB);
  u16* Wvb = (u16*)(ws + 28 * WSMB);
  u16* Wob = (u16*)(ws + 30 * WSMB);
  u16* Qb = (u16*)(ws + 32 * WSMB);
  u16* Kb = (u16*)(ws + 40 * WSMB);
  u16* V4 = (u16*)(ws + 48 * WSMB);
  u64* bits = (u64*)(ws + 56 * WSMB);
  u64* MBm = (u64*)(ws + 57 * WSMB);  // own slot: mm now concurrent with GEMM
  u16* xbuf = Xq;

  k_prep<<<17408, 256, 0, stream>>>(query, key_, value, Wq, Wk, Wv, Wo, mask,
                                    Xq, Xk, Xv, Wqb, Wkb, Wvb, Wob, bits);
  k_qkv<<<1792, 256, 0, stream>>>(Xq, Xk, Xv, Wqb, Wkb, Wvb, bq, bk, bv, Qb,
                                  Kb, V4, bits, MBm);
  k_attn<<<512, 256, 0, stream>>>(Qb, Kb, V4, MBm, xbuf);
  k_oproj<<<512, 256, 0, stream>>>(xbuf, Wob, (float*)d_out);
}